// Round 11
// baseline (215.526 us; speedup 1.0000x reference)
//
#include <hip/hip_runtime.h>

#define HH 512
#define WW 512
#define RSTRIP 8           // output rows per single-wave block (4096 blocks)
#define PWC 520            // padded VS row: [4 zeros][512][4 zeros]

// NCC, barrier-free single-wave edition.
//  - Block = 1 wave (64 threads). Lane owns 8 cols (c0 = 8*lane); the wave
//    spans the full 512-col row, so the horizontal fold's halo lives in a
//    per-block LDS plane with NO barrier (intra-wave DS ops are ordered).
//  - VS[5][8] = running 9-row vertical sums of the 5 products, in registers.
//  - Lead/trail rows arrive via a TRUE 2-step-ahead register prefetch
//    (ping-pong banks, fully unrolled -> static indices). No per-step
//    vmcnt(0): consumption happens two steps after issue (>1000 cy slack).
//  - Trail rows are this wave's own recent loads -> L1-hot.
__global__ __launch_bounds__(64) void ncc_kernel(const float* __restrict__ I,
                                                 const float* __restrict__ J,
                                                 float* __restrict__ ws) {
    __shared__ float vsrow[5][PWC];          // 10,400 B, single-buffered
    const int L = threadIdx.x;               // lane, owns cols 8L..8L+7
    const int c0 = L << 3;
    const int b = blockIdx.x >> 6;           // image (64 strips per image)
    const int r0 = (blockIdx.x & 63) << 3;   // strip base row

    const float* Ib = I + (size_t)b * (HH * WW);
    const float* Jb = J + (size_t)b * (HH * WW);

    // zero the pads once (lanes 0..39; intra-wave ordering, no barrier)
    if (L < 40) {
        const int p = L >> 3, k = L & 7;
        vsrow[p][(k < 4) ? k : (512 + k)] = 0.f;
    }

    // ---- warmup: VS = sum of products over rows r0-4 .. r0+4 ----
    float VS[5][8];
#pragma unroll
    for (int p = 0; p < 5; ++p)
#pragma unroll
        for (int c = 0; c < 8; ++c) VS[p][c] = 0.f;

#pragma unroll
    for (int s = 0; s < 9; ++s) {
        const int r = r0 - 4 + s;
        if (r >= 0) {                        // uniform; false only on strip 0
            const float4* ip = reinterpret_cast<const float4*>(Ib + (size_t)r * WW + c0);
            const float4* jp = reinterpret_cast<const float4*>(Jb + (size_t)r * WW + c0);
            const float4 i4a = ip[0], i4b = ip[1], j4a = jp[0], j4b = jp[1];
            const float iv[8] = {i4a.x, i4a.y, i4a.z, i4a.w, i4b.x, i4b.y, i4b.z, i4b.w};
            const float jv[8] = {j4a.x, j4a.y, j4a.z, j4a.w, j4b.x, j4b.y, j4b.z, j4b.w};
#pragma unroll
            for (int c = 0; c < 8; ++c) {
                VS[0][c] += iv[c];
                VS[1][c] += jv[c];
                VS[2][c] = fmaf(iv[c], iv[c], VS[2][c]);
                VS[3][c] = fmaf(jv[c], jv[c], VS[3][c]);
                VS[4][c] = fmaf(iv[c], jv[c], VS[4][c]);
            }
        }
    }

    // ---- prefetch banks: bank (h&1) holds rows for step h, issued 2 early ----
    float4 pLi[2][2], pLj[2][2], pTi[2][2], pTj[2][2];
    {
        const int jt1 = (r0 - 4 < 0) ? 0 : r0 - 4;   // trail for h=1
        const int jt2 = (r0 - 3 < 0) ? 0 : r0 - 3;   // trail for h=2
        const float4* p;
        p = reinterpret_cast<const float4*>(Ib + (size_t)(r0 + 5) * WW + c0); pLi[1][0] = p[0]; pLi[1][1] = p[1];
        p = reinterpret_cast<const float4*>(Jb + (size_t)(r0 + 5) * WW + c0); pLj[1][0] = p[0]; pLj[1][1] = p[1];
        p = reinterpret_cast<const float4*>(Ib + (size_t)jt1 * WW + c0);      pTi[1][0] = p[0]; pTi[1][1] = p[1];
        p = reinterpret_cast<const float4*>(Jb + (size_t)jt1 * WW + c0);      pTj[1][0] = p[0]; pTj[1][1] = p[1];
        p = reinterpret_cast<const float4*>(Ib + (size_t)(r0 + 6) * WW + c0); pLi[0][0] = p[0]; pLi[0][1] = p[1];
        p = reinterpret_cast<const float4*>(Jb + (size_t)(r0 + 6) * WW + c0); pLj[0][0] = p[0]; pLj[0][1] = p[1];
        p = reinterpret_cast<const float4*>(Ib + (size_t)jt2 * WW + c0);      pTi[0][0] = p[0]; pTi[0][1] = p[1];
        p = reinterpret_cast<const float4*>(Jb + (size_t)jt2 * WW + c0);      pTj[0][0] = p[0]; pTj[0][1] = p[1];
    }

    const float inv81 = 1.f / 81.f;
    float acc = 0.f;

#pragma unroll
    for (int h = 0; h < RSTRIP; ++h) {       // FULL unroll: bank indices static
        if (h >= 1) {
            const int bk = h & 1;
            // VS update for output row r0+h: +lead (r0+h+4), -trail (r0+h-5)
            if (r0 + h + 4 < HH) {           // uniform (bottom strips only)
                const float lv[8] = {pLi[bk][0].x, pLi[bk][0].y, pLi[bk][0].z, pLi[bk][0].w,
                                     pLi[bk][1].x, pLi[bk][1].y, pLi[bk][1].z, pLi[bk][1].w};
                const float mv[8] = {pLj[bk][0].x, pLj[bk][0].y, pLj[bk][0].z, pLj[bk][0].w,
                                     pLj[bk][1].x, pLj[bk][1].y, pLj[bk][1].z, pLj[bk][1].w};
#pragma unroll
                for (int c = 0; c < 8; ++c) {
                    VS[0][c] += lv[c];
                    VS[1][c] += mv[c];
                    VS[2][c] = fmaf(lv[c], lv[c], VS[2][c]);
                    VS[3][c] = fmaf(mv[c], mv[c], VS[3][c]);
                    VS[4][c] = fmaf(lv[c], mv[c], VS[4][c]);
                }
            }
            if (r0 + h - 5 >= 0) {           // uniform (strip 0, h<=4 skips)
                const float tv[8] = {pTi[bk][0].x, pTi[bk][0].y, pTi[bk][0].z, pTi[bk][0].w,
                                     pTi[bk][1].x, pTi[bk][1].y, pTi[bk][1].z, pTi[bk][1].w};
                const float uv[8] = {pTj[bk][0].x, pTj[bk][0].y, pTj[bk][0].z, pTj[bk][0].w,
                                     pTj[bk][1].x, pTj[bk][1].y, pTj[bk][1].z, pTj[bk][1].w};
#pragma unroll
                for (int c = 0; c < 8; ++c) {
                    VS[0][c] -= tv[c];
                    VS[1][c] -= uv[c];
                    VS[2][c] = fmaf(-tv[c], tv[c], VS[2][c]);
                    VS[3][c] = fmaf(-uv[c], uv[c], VS[3][c]);
                    VS[4][c] = fmaf(-tv[c], uv[c], VS[4][c]);
                }
            }
            // refill bank bk with rows for step h+2 (consumed 2 steps later)
            if (h + 2 <= RSTRIP - 1) {
                const int jl = (r0 + h + 6 > HH - 1) ? HH - 1 : r0 + h + 6;
                const int jt = (r0 + h - 3 < 0) ? 0 : r0 + h - 3;
                const float4* p;
                p = reinterpret_cast<const float4*>(Ib + (size_t)jl * WW + c0); pLi[bk][0] = p[0]; pLi[bk][1] = p[1];
                p = reinterpret_cast<const float4*>(Jb + (size_t)jl * WW + c0); pLj[bk][0] = p[0]; pLj[bk][1] = p[1];
                p = reinterpret_cast<const float4*>(Ib + (size_t)jt * WW + c0); pTi[bk][0] = p[0]; pTi[bk][1] = p[1];
                p = reinterpret_cast<const float4*>(Jb + (size_t)jt * WW + c0); pTj[bk][0] = p[0]; pTj[bk][1] = p[1];
            }
        }

        // publish VS (own 8 cols) -- intra-wave, no barrier needed
#pragma unroll
        for (int p = 0; p < 5; ++p) {
            *reinterpret_cast<float4*>(&vsrow[p][4 + c0]) =
                make_float4(VS[p][0], VS[p][1], VS[p][2], VS[p][3]);
            *reinterpret_cast<float4*>(&vsrow[p][8 + c0]) =
                make_float4(VS[p][4], VS[p][5], VS[p][6], VS[p][7]);
        }

        // read 16-col windows (4 aligned b128 per product) + fold + cc
        float box[5][8];
#pragma unroll
        for (int p = 0; p < 5; ++p) {
            const float4* q = reinterpret_cast<const float4*>(&vsrow[p][c0]);
            const float4 w0 = q[0], w1 = q[1], w2 = q[2], w3 = q[3];
            const float w[16] = {w0.x, w0.y, w0.z, w0.w, w1.x, w1.y, w1.z, w1.w,
                                 w2.x, w2.y, w2.z, w2.w, w3.x, w3.y, w3.z, w3.w};
            float s = (((w[0] + w[1]) + (w[2] + w[3])) +
                       ((w[4] + w[5]) + (w[6] + w[7]))) + w[8];
            box[p][0] = s;
#pragma unroll
            for (int o = 1; o < 8; ++o) {
                s += w[o + 8] - w[o - 1];
                box[p][o] = s;
            }
        }
#pragma unroll
        for (int o = 0; o < 8; ++o) {
            const float IS = box[0][o], JS = box[1][o];
            const float I2 = box[2][o], J2 = box[3][o], IJ = box[4][o];
            const float cross = fmaf(-(IS * JS), inv81, IJ);
            const float Iv = fmaf(-(IS * IS), inv81, I2);
            const float Jv = fmaf(-(JS * JS), inv81, J2);
            acc = fmaf(cross * cross,
                       __builtin_amdgcn_rcpf(fmaf(Iv, Jv, 1e-5f)), acc);
        }
    }

    // wave reduction + one atomic per block
#pragma unroll
    for (int off = 32; off; off >>= 1) acc += __shfl_down(acc, off);
    if (L == 0) atomicAdd(&ws[0], acc);
}

// reg: EXACT R6/R8 configuration (measured fast): 1024 blocks, 32-row
// register-carried strips, 2 strips per 256-thread block. DO NOT TOUCH.
__global__ __launch_bounds__(256) void reg_kernel(const float* __restrict__ P,
                                                  float* __restrict__ ws) {
    __shared__ float sh[8];
    const int T = threadIdx.x;
    const int c4 = T & 127;                         // 128 float4s = one row
    const int strip = (blockIdx.x << 1) | (T >> 7); // 0..2047 over 65536 rows
    const size_t row0 = (size_t)strip << 5;         // *32 rows per strip
    const bool slast = ((strip & 15) == 15);        // ends at image row 511
    const float* rp = P + row0 * WW + (c4 << 2);

    float sdx = 0.f, sdy = 0.f;
    float4 cur = *reinterpret_cast<const float4*>(rp);
#pragma unroll 8
    for (int i = 0; i < 32; ++i) {
        float d0 = cur.y - cur.x, d1 = cur.z - cur.y, d2 = cur.w - cur.z;
        sdx += d0 * d0 + d1 * d1 + d2 * d2;
        if (c4 < 127) {                             // neighbor elem (cache hit)
            float nx = rp[(size_t)i * WW + 4];
            float d3 = nx - cur.w;
            sdx += d3 * d3;
        }
        if (i < 31) {
            float4 nr = *reinterpret_cast<const float4*>(rp + (size_t)(i + 1) * WW);
            float e0 = nr.x - cur.x, e1 = nr.y - cur.y;
            float e2 = nr.z - cur.z, e3 = nr.w - cur.w;
            sdy += e0 * e0 + e1 * e1 + e2 * e2 + e3 * e3;
            cur = nr;
        } else if (!slast) {
            float4 nr = *reinterpret_cast<const float4*>(rp + (size_t)32 * WW);
            float e0 = nr.x - cur.x, e1 = nr.y - cur.y;
            float e2 = nr.z - cur.z, e3 = nr.w - cur.w;
            sdy += e0 * e0 + e1 * e1 + e2 * e2 + e3 * e3;
        }
    }

#pragma unroll
    for (int off = 32; off; off >>= 1) {
        sdx += __shfl_down(sdx, off);
        sdy += __shfl_down(sdy, off);
    }
    if ((T & 63) == 0) { sh[T >> 6] = sdx; sh[4 + (T >> 6)] = sdy; }
    __syncthreads();
    if (T == 0) {
        atomicAdd(&ws[1], sh[0] + sh[1] + sh[2] + sh[3]);
        atomicAdd(&ws[2], sh[4] + sh[5] + sh[6] + sh[7]);
    }
}

__global__ void finalize_kernel(const float* __restrict__ ws,
                                float* __restrict__ out) {
    float cc_sum = ws[0], dx_sum = ws[1], dy_sum = ws[2];
    float loss_sim = -(cc_sum / 16777216.f);   // 64*512*512
    float mdx = dx_sum / 33488896.f;           // 64*2*512*511
    float mdy = dy_sum / 33488896.f;           // 64*2*511*512
    float loss_reg = (mdx + mdy) * 0.5f * 0.1f;
    out[0] = loss_sim;
    out[1] = loss_reg;
    out[2] = loss_sim + loss_reg;
}

extern "C" void kernel_launch(void* const* d_in, const int* in_sizes, int n_in,
                              void* d_out, int out_size, void* d_ws, size_t ws_size,
                              hipStream_t stream) {
    const float* I = (const float*)d_in[0];   // target_proj
    const float* J = (const float*)d_in[1];   // warped_moving
    const float* P = (const float*)d_in[2];   // phi
    float* out = (float*)d_out;
    float* ws = (float*)d_ws;

    hipMemsetAsync(d_ws, 0, 3 * sizeof(float), stream);
    ncc_kernel<<<4096, 64, 0, stream>>>(I, J, ws);   // single-wave blocks
    reg_kernel<<<1024, 256, 0, stream>>>(P, ws);     // R6 config
    finalize_kernel<<<1, 1, 0, stream>>>(ws, out);
}

// Round 12
// 101.851 us; speedup vs baseline: 2.1161x; 2.1161x over previous
//
#include <hip/hip_runtime.h>

#define HH 512
#define WW 512
#define RSTRIP 16          // output rows per block (2048 blocks, 32 strips/image)
#define PWC 520            // padded VS row: [4 zeros][512][4 zeros]

// NCC, deep-slack register-ring edition (R10 + ONE change: ring depth 12 with
// loads issued directly into the freed slot -> no per-step vmcnt(0); first
// use of each load is 3 steps (~2000 cy) later, compiler emits counted waits).
//  - 256 threads/block (4 waves); lane owns 2 cols (c0 = 2T); block = 16-row strip.
//  - slot s holds row r0+s-4 at loop entry; at step h: trail row r0+h-4 is in
//    slot h%12; after trail-sub that slot receives row r0+h+8.
//  - Horizontal 9-window via LDS fold of the 5 vertical sums (double-buffered,
//    one barrier/step, aligned float2 ops).
__global__ __launch_bounds__(256) void ncc_kernel(const float* __restrict__ I,
                                                  const float* __restrict__ J,
                                                  float* __restrict__ ws) {
    __shared__ float vs[2][5][PWC];             // 20,800 B
    const int T = threadIdx.x;                  // owns cols 2T, 2T+1
    const int c0 = T << 1;
    const int b = blockIdx.x >> 5;              // image
    const int r0 = (blockIdx.x & 31) << 4;      // strip base row

    const float* Ib = I + (size_t)b * (HH * WW);
    const float* Jb = J + (size_t)b * (HH * WW);

    // zero the column pads once: 2 bufs x 5 products x 8 pad floats = 80
    if (T < 80) {
        const int buf = T / 40, rem = T % 40, p = rem >> 3, k = rem & 7;
        vs[buf][p][(k < 4) ? k : (512 + k)] = 0.f;
    }

    // ---- register ring: slot s holds row r0+s-4 (s = 0..11) ----
    float2 hi[12], hj[12];
#pragma unroll
    for (int s = 0; s < 12; ++s) {
        const int r = r0 + s - 4;               // r0+7 <= 487: no high clamp
        if (r >= 0) {                           // uniform branch (strip 0 only)
            hi[s] = *reinterpret_cast<const float2*>(Ib + (size_t)r * WW + c0);
            hj[s] = *reinterpret_cast<const float2*>(Jb + (size_t)r * WW + c0);
        } else {                                // zero-pad above the image
            hi[s] = make_float2(0.f, 0.f);
            hj[s] = make_float2(0.f, 0.f);
        }
    }

    // ---- warm-up: VS = sum of products over slots 0..8 (rows r0-4..r0+4) ----
    float VS[5][2] = {{0.f, 0.f}};
#pragma unroll
    for (int s = 0; s <= 8; ++s) {              // zeros contribute nothing
        const float i0 = hi[s].x, i1 = hi[s].y;
        const float j0 = hj[s].x, j1 = hj[s].y;
        VS[0][0] += i0;                 VS[0][1] += i1;
        VS[1][0] += j0;                 VS[1][1] += j1;
        VS[2][0] = fmaf(i0, i0, VS[2][0]); VS[2][1] = fmaf(i1, i1, VS[2][1]);
        VS[3][0] = fmaf(j0, j0, VS[3][0]); VS[3][1] = fmaf(j1, j1, VS[3][1]);
        VS[4][0] = fmaf(i0, j0, VS[4][0]); VS[4][1] = fmaf(i1, j1, VS[4][1]);
    }

    const float inv81 = 1.f / 81.f;
    float acc = 0.f;

#pragma unroll
    for (int h = 0; h < RSTRIP; ++h) {          // FULL unroll: indices static
        // 1. publish VS for output row r0+h
#pragma unroll
        for (int p = 0; p < 5; ++p)
            *reinterpret_cast<float2*>(&vs[h & 1][p][4 + c0]) =
                make_float2(VS[p][0], VS[p][1]);

        // 2. VS update toward row r0+h+1:
        //    trail = slot h%12 (row r0+h-4); negative rows are zeros -> no gate
        {
            const float2 ti = hi[h % 12], tj = hj[h % 12];
            VS[0][0] -= ti.x;                 VS[0][1] -= ti.y;
            VS[1][0] -= tj.x;                 VS[1][1] -= tj.y;
            VS[2][0] = fmaf(-ti.x, ti.x, VS[2][0]); VS[2][1] = fmaf(-ti.y, ti.y, VS[2][1]);
            VS[3][0] = fmaf(-tj.x, tj.x, VS[3][0]); VS[3][1] = fmaf(-tj.y, tj.y, VS[3][1]);
            VS[4][0] = fmaf(-ti.x, tj.x, VS[4][0]); VS[4][1] = fmaf(-ti.y, tj.y, VS[4][1]);
        }
        // 3. refill the freed slot with row r0+h+8 (first used 3 steps later;
        //    clamped source rows beyond the image are loaded but never added)
        {
            const int rr = r0 + h + 8;
            const int rc = rr > HH - 1 ? HH - 1 : rr;
            hi[h % 12] = *reinterpret_cast<const float2*>(Ib + (size_t)rc * WW + c0);
            hj[h % 12] = *reinterpret_cast<const float2*>(Jb + (size_t)rc * WW + c0);
        }
        // 4. lead = slot (h+9)%12 (row r0+h+5), gated at the image bottom
        if (r0 + h + 5 < HH) {                  // uniform branch
            const float2 li = hi[(h + 9) % 12], lj = hj[(h + 9) % 12];
            VS[0][0] += li.x;                 VS[0][1] += li.y;
            VS[1][0] += lj.x;                 VS[1][1] += lj.y;
            VS[2][0] = fmaf(li.x, li.x, VS[2][0]); VS[2][1] = fmaf(li.y, li.y, VS[2][1]);
            VS[3][0] = fmaf(lj.x, lj.x, VS[3][0]); VS[3][1] = fmaf(lj.y, lj.y, VS[3][1]);
            VS[4][0] = fmaf(li.x, lj.x, VS[4][0]); VS[4][1] = fmaf(li.y, lj.y, VS[4][1]);
        }

        __syncthreads();                        // vs[h&1] fully written

        // 5. window read (5 aligned float2s = floats c0..c0+9 of padded row)
        //    + fresh 9-wide fold -> box for 2 output cols
        float box[5][2];
#pragma unroll
        for (int p = 0; p < 5; ++p) {
            const float2* q = reinterpret_cast<const float2*>(&vs[h & 1][p][0]) + T;
            float2 a = q[0], bb = q[1], c = q[2], d = q[3], e = q[4];
            float s = (((a.x + a.y) + (bb.x + bb.y)) +
                       ((c.x + c.y) + (d.x + d.y))) + e.x;
            box[p][0] = s;
            box[p][1] = s + (e.y - a.x);
        }
#pragma unroll
        for (int o = 0; o < 2; ++o) {
            const float IS = box[0][o], JS = box[1][o];
            const float I2 = box[2][o], J2 = box[3][o], IJ = box[4][o];
            const float cross = fmaf(-(IS * JS), inv81, IJ);
            const float Iv = fmaf(-(IS * IS), inv81, I2);
            const float Jv = fmaf(-(JS * JS), inv81, J2);
            acc = fmaf(cross * cross,
                       __builtin_amdgcn_rcpf(fmaf(Iv, Jv, 1e-5f)), acc);
        }
    }

    // block reduction (4 waves)
#pragma unroll
    for (int off = 32; off; off >>= 1) acc += __shfl_down(acc, off);
    __syncthreads();
    if ((T & 63) == 0) vs[0][0][T >> 6] = acc;
    __syncthreads();
    if (T == 0)
        atomicAdd(&ws[0], (vs[0][0][0] + vs[0][0][1]) +
                          (vs[0][0][2] + vs[0][0][3]));
}

// reg: EXACT R6/R8 configuration (measured ~21-22 us): 1024 blocks, 32-row
// register-carried strips, 2 strips per 256-thread block. DO NOT TOUCH.
__global__ __launch_bounds__(256) void reg_kernel(const float* __restrict__ P,
                                                  float* __restrict__ ws) {
    __shared__ float sh[8];
    const int T = threadIdx.x;
    const int c4 = T & 127;                         // 128 float4s = one row
    const int strip = (blockIdx.x << 1) | (T >> 7); // 0..2047 over 65536 rows
    const size_t row0 = (size_t)strip << 5;         // *32 rows per strip
    const bool slast = ((strip & 15) == 15);        // ends at image row 511
    const float* rp = P + row0 * WW + (c4 << 2);

    float sdx = 0.f, sdy = 0.f;
    float4 cur = *reinterpret_cast<const float4*>(rp);
#pragma unroll 8
    for (int i = 0; i < 32; ++i) {
        float d0 = cur.y - cur.x, d1 = cur.z - cur.y, d2 = cur.w - cur.z;
        sdx += d0 * d0 + d1 * d1 + d2 * d2;
        if (c4 < 127) {                             // neighbor elem (cache hit)
            float nx = rp[(size_t)i * WW + 4];
            float d3 = nx - cur.w;
            sdx += d3 * d3;
        }
        if (i < 31) {
            float4 nr = *reinterpret_cast<const float4*>(rp + (size_t)(i + 1) * WW);
            float e0 = nr.x - cur.x, e1 = nr.y - cur.y;
            float e2 = nr.z - cur.z, e3 = nr.w - cur.w;
            sdy += e0 * e0 + e1 * e1 + e2 * e2 + e3 * e3;
            cur = nr;
        } else if (!slast) {
            float4 nr = *reinterpret_cast<const float4*>(rp + (size_t)32 * WW);
            float e0 = nr.x - cur.x, e1 = nr.y - cur.y;
            float e2 = nr.z - cur.z, e3 = nr.w - cur.w;
            sdy += e0 * e0 + e1 * e1 + e2 * e2 + e3 * e3;
        }
    }

#pragma unroll
    for (int off = 32; off; off >>= 1) {
        sdx += __shfl_down(sdx, off);
        sdy += __shfl_down(sdy, off);
    }
    if ((T & 63) == 0) { sh[T >> 6] = sdx; sh[4 + (T >> 6)] = sdy; }
    __syncthreads();
    if (T == 0) {
        atomicAdd(&ws[1], sh[0] + sh[1] + sh[2] + sh[3]);
        atomicAdd(&ws[2], sh[4] + sh[5] + sh[6] + sh[7]);
    }
}

__global__ void finalize_kernel(const float* __restrict__ ws,
                                float* __restrict__ out) {
    float cc_sum = ws[0], dx_sum = ws[1], dy_sum = ws[2];
    float loss_sim = -(cc_sum / 16777216.f);   // 64*512*512
    float mdx = dx_sum / 33488896.f;           // 64*2*512*511
    float mdy = dy_sum / 33488896.f;           // 64*2*511*512
    float loss_reg = (mdx + mdy) * 0.5f * 0.1f;
    out[0] = loss_sim;
    out[1] = loss_reg;
    out[2] = loss_sim + loss_reg;
}

extern "C" void kernel_launch(void* const* d_in, const int* in_sizes, int n_in,
                              void* d_out, int out_size, void* d_ws, size_t ws_size,
                              hipStream_t stream) {
    const float* I = (const float*)d_in[0];   // target_proj
    const float* J = (const float*)d_in[1];   // warped_moving
    const float* P = (const float*)d_in[2];   // phi
    float* out = (float*)d_out;
    float* ws = (float*)d_ws;

    hipMemsetAsync(d_ws, 0, 3 * sizeof(float), stream);
    ncc_kernel<<<2048, 256, 0, stream>>>(I, J, ws);  // 20.8 KB LDS
    reg_kernel<<<1024, 256, 0, stream>>>(P, ws);     // R6 config, ~21 us
    finalize_kernel<<<1, 1, 0, stream>>>(ws, out);
}